// Round 4
// baseline (255.955 us; speedup 1.0000x reference)
//
#include <hip/hip_runtime.h>
#include <hip/hip_bf16.h>

#define BB   8
#define TT   1024
#define NCBN 2
#define DD   128
#define KK   8192
#define MM   8192          // B*T queries per codebook

constexpr int OUT_IDX_OFF  = BB * 256 * TT;                // 2097152
constexpr int OUT_LOSS_OFF = OUT_IDX_OFF + BB * NCBN * TT; // 2113536

#define THR   0.45f        // >= 2*worst-case |y_bf16 - y_f32| (bound ~0.34)
#define QCAP  2048
#define SCAP  2048         // per-block global spill capacity (entries)

typedef __attribute__((ext_vector_type(8))) short   short8;   // 8 bf16
typedef __attribute__((ext_vector_type(4))) float   float4v;

__device__ __forceinline__ unsigned short f2bf(float v) {
    unsigned u = __float_as_uint(v);
    return (unsigned short)((u + 0x7FFFu + ((u >> 16) & 1u)) >> 16);  // RNE
}

// round toward -inf: stored value <= true value (superset-safe screen filter)
__device__ __forceinline__ unsigned short f2bf_dn(float v) {
    unsigned u = __float_as_uint(v);
    unsigned short h = (unsigned short)(u >> 16);
    if ((u & 0x80000000u) && (u & 0xFFFFu)) ++h;   // negative: truncation went up
    return h;
}

__device__ __forceinline__ void gl_lds16(const void* g, void* l) {
    __builtin_amdgcn_global_load_lds(
        (const __attribute__((address_space(1))) unsigned int*)g,
        (__attribute__((address_space(3))) unsigned int*)l, 16, 0, 0);
}

// ---------------------------------------------------------------------------
// Merged pack kernel (one dispatch instead of two):
//   blocks 0..255  : pack_x role — transpose (B,256,T) -> xbf bf16 + x2 + pmin
//   blocks 256..319: pack_c role — codebooks -> cbf bf16 + c2 + zero loss slot
// ---------------------------------------------------------------------------
__global__ __launch_bounds__(256)
void pack_kernel(const float* __restrict__ x, const float* __restrict__ cb,
                 unsigned short* __restrict__ xbf, unsigned short* __restrict__ cbf,
                 float* __restrict__ x2, float* __restrict__ c2,
                 unsigned long long* __restrict__ pmin, float* __restrict__ out) {
    __shared__ float Ld[DD][65];
    const int gb  = blockIdx.x;
    const int tid = threadIdx.x;

    if (gb < 256) {
        // ---- pack_x role: bxn = gb&15 -> (b,n); ty = gb>>4 -> t-tile
        const int bxn = gb & 15, ty = gb >> 4;
        const int b = bxn >> 1, n = bxn & 1;
        const int t0 = ty * 64;

        const float* base = x + ((size_t)(b * 256 + n * 128)) * TT + t0;
        const int dro = tid >> 2, q4 = tid & 3;
#pragma unroll
        for (int half = 0; half < 2; ++half) {
            int d = dro + half * 64;
            const float* rp = base + (size_t)d * TT + q4 * 16;
#pragma unroll
            for (int j = 0; j < 4; ++j) {
                float4 v = *(const float4*)(rp + j * 4);
                int t = q4 * 16 + j * 4;
                Ld[d][t + 0] = v.x; Ld[d][t + 1] = v.y;
                Ld[d][t + 2] = v.z; Ld[d][t + 3] = v.w;
            }
        }
        __syncthreads();

        if (tid < 64) {
            float s = 0.f;
            for (int d = 0; d < DD; ++d) { float v = Ld[d][tid]; s = fmaf(v, v, s); }
            x2[(size_t)n * MM + b * TT + t0 + tid] = s;
            pmin[(size_t)n * MM + b * TT + t0 + tid] = 0xFFFFFFFFFFFFFFFFull;
        }

        unsigned short* orow0 = xbf + ((size_t)n * MM + b * TT + t0) * DD;
#pragma unroll
        for (int pp = 0; pp < 4; ++pp) {
            int u = tid + pp * 256;            // 1024 units = 64 rows x 16 segs
            int tt = u >> 4, sg = u & 15;
            unsigned short tmp[8];
#pragma unroll
            for (int j = 0; j < 8; ++j) tmp[j] = f2bf(Ld[sg * 8 + j][tt]);
            uint4 pk;
            pk.x = (unsigned)tmp[0] | ((unsigned)tmp[1] << 16);
            pk.y = (unsigned)tmp[2] | ((unsigned)tmp[3] << 16);
            pk.z = (unsigned)tmp[4] | ((unsigned)tmp[5] << 16);
            pk.w = (unsigned)tmp[6] | ((unsigned)tmp[7] << 16);
            *(uint4*)(orow0 + (size_t)tt * DD + sg * 8) = pk;
        }
    } else {
        // ---- pack_c role
        int g = (gb - 256) * 256 + tid;        // n*K + k
        if (g == 0) out[OUT_LOSS_OFF] = 0.f;
        const float4* crow = (const float4*)(cb + (size_t)g * DD);
        unsigned short* orow = cbf + (size_t)g * DD;
        float s = 0.f;
#pragma unroll 4
        for (int i2 = 0; i2 < 16; ++i2) {
            float4 v0 = crow[2 * i2];
            float4 v1 = crow[2 * i2 + 1];
            s = fmaf(v0.x, v0.x, s); s = fmaf(v0.y, v0.y, s);
            s = fmaf(v0.z, v0.z, s); s = fmaf(v0.w, v0.w, s);
            s = fmaf(v1.x, v1.x, s); s = fmaf(v1.y, v1.y, s);
            s = fmaf(v1.z, v1.z, s); s = fmaf(v1.w, v1.w, s);
            uint4 pk;
            pk.x = (unsigned)f2bf(v0.x) | ((unsigned)f2bf(v0.y) << 16);
            pk.y = (unsigned)f2bf(v0.z) | ((unsigned)f2bf(v0.w) << 16);
            pk.z = (unsigned)f2bf(v1.x) | ((unsigned)f2bf(v1.y) << 16);
            pk.w = (unsigned)f2bf(v1.z) | ((unsigned)f2bf(v1.w) << 16);
            *(uint4*)(orow + i2 * 8) = pk;
        }
        c2[g] = s;
    }
}

// ---------------------------------------------------------------------------
// Exact fp32 rescore: identical association to the R1 passing kernel.
// atomicMin on packed (s_bits<<32 | k) = "min s, then lowest k" (s > 0 here).
// ---------------------------------------------------------------------------
__device__ void rescore_one(int n, int m, int k,
                            const float* __restrict__ x, const float* __restrict__ cb,
                            const float* __restrict__ x2, const float* __restrict__ c2,
                            unsigned long long* __restrict__ pmin) {
    int b = m >> 10, t = m & (TT - 1);
    const float* xp = x + ((size_t)(b * 256 + n * 128)) * TT + t;
    const float* cp = cb + ((size_t)(n * KK + k)) * DD;
    float xc = 0.f;
    for (int d = 0; d < DD; ++d)
        xc = fmaf(xp[(size_t)d * TT], cp[d], xc);
    float u = x2[n * MM + m] - 2.0f * xc;
    float s = u + c2[n * KK + k];
    unsigned long long pk = ((unsigned long long)__float_as_uint(s) << 32) | (unsigned)k;
    atomicMin(pmin + (size_t)n * MM + m, pk);
}

// ---------------------------------------------------------------------------
// Screening v9: 8-wave single-pass with
//   - two-pass epilogue: chunk min merged FIRST, enqueue under
//     te = min(prefix thr, cmin_wave + THR)  (superset-safe tightener);
//   - it=0 enqueues chunk 0 under its own self-min (te = cmin0 + THR), so no
//     chunk-0 revisit: 16 GEMM iterations total;
//   - overflow past QCAP goes to a per-block GLOBAL spill buffer (cheap
//     store) instead of an inline divergent rescore; the drain re-filters
//     queue+spill against the FINAL threshold before any fp32 rescore.
//     (scap==0 falls back to inline rescore — still correct.)
// grid 512 x 512 threads (2 blocks/CU). combo = id&7 -> (n,ks) per XCD.
// ---------------------------------------------------------------------------
__global__ __launch_bounds__(512, 4)
void screen_kernel(const unsigned short* __restrict__ xbf,
                   const unsigned short* __restrict__ cbf,
                   const float* __restrict__ c2,
                   const float* __restrict__ x,
                   const float* __restrict__ cb32,
                   const float* __restrict__ x2,
                   unsigned long long* __restrict__ pmin,
                   unsigned long long* __restrict__ spill, int scap) {
    __shared__ __align__(16) unsigned short Csh[2][128 * 128];  // 64 KB
    __shared__ float          c2s[2][128];                      // 1 KB
    __shared__ unsigned int   minU[128];
    __shared__ unsigned int   qcnt;
    __shared__ unsigned int   queue[QCAP];                      // 8 KB
    __shared__ unsigned short queueY[QCAP];                     // 4 KB

    const int tid = threadIdx.x;
    const int id  = blockIdx.x;
    const int n   = id & 1;
    const int ks  = (id >> 1) & 3;
    const int qt  = id >> 3;           // 0..63
    const int m0  = qt * 128;
    const int k0  = ks * 2048;

    const int wave = tid >> 6, lane = tid & 63;
    const int cw = wave & 1, qw = wave >> 1;       // cw: 2x64 codes, qw: 4x32 queries
    const int quad = lane >> 4, l15 = lane & 15;

    unsigned long long* spillp = spill + (size_t)id * (size_t)(scap > 0 ? scap : 1);

    // per-lane staging offsets (bytes within one 32 KB tile), 4 issues/wave
    int goff[4];
#pragma unroll
    for (int p = 0; p < 4; ++p) {
        int u   = (p * 8 + wave) * 64 + lane;
        int row = u >> 4;
        int seg = (u & 15) ^ (row & 15);
        goff[p] = (row * DD + seg * 8) * 2;
    }

    const char*  asrc0 = (const char*)(cbf + ((size_t)n * KK + k0) * DD);
    const float* c2p   = c2 + (size_t)n * KK + k0;

    // ---- prologue: stage queries -> Csh[0], code chunk 0 -> Csh[1] (async)
    {
        const char* qsrc = (const char*)(xbf + ((size_t)n * MM + m0) * DD);
#pragma unroll
        for (int p = 0; p < 4; ++p)
            gl_lds16(qsrc + goff[p], &Csh[0][(p * 8 + wave) * 512]);
#pragma unroll
        for (int p = 0; p < 4; ++p)
            gl_lds16(asrc0 + goff[p], &Csh[1][(p * 8 + wave) * 512]);
    }
    if (tid < 32)  *(float4*)&c2s[1][tid * 4] = *(const float4*)(c2p + tid * 4);
    if (tid < 128) minU[tid] = 0xFFFFFFFFu;
    if (tid == 0)  qcnt = 0;
    __syncthreads();                   // both stages + c2s drained

    // ---- query B-fragments (whole D=128) register-resident: 32 VGPRs
    short8 bfr[2][4];                      // [tq][k4]
#pragma unroll
    for (int tq = 0; tq < 2; ++tq) {
        int q = qw * 32 + tq * 16 + l15;   // q&15 == l15
#pragma unroll
        for (int k4 = 0; k4 < 4; ++k4) {
            int seg = k4 * 4 + quad;
            bfr[tq][k4] = *(const short8*)(&Csh[0][q * 128 + ((seg ^ l15) * 8)]);
        }
    }
    __syncthreads();                   // bfr reads done; Csh[0] reusable

    float thr[2] = {3.4e38f, 3.4e38f};

    for (int it = 0; it < 16; ++it) {
        const int sb   = it & 1;       // stage buffer (next chunk)
        const int cbuf = sb ^ 1;       // compute buffer (current chunk)

        if (it < 15) {                 // issue next-chunk stage
            const int dn = it + 1;
            const char* src = asrc0 + (size_t)dn * (128 * DD * 2);
#pragma unroll
            for (int p = 0; p < 4; ++p)
                gl_lds16(src + goff[p], &Csh[sb][(p * 8 + wave) * 512]);
            if (tid < 32)
                *(float4*)&c2s[sb][tid * 4] =
                    *(const float4*)(c2p + dn * 128 + tid * 4);
        }

        // ---- compute chunk `it` from Csh[cbuf]: 32 MFMA/wave
        float4v acc[4][2];             // [tc][tq]: 32 VGPRs
#pragma unroll
        for (int tc = 0; tc < 4; ++tc)
#pragma unroll
            for (int tq = 0; tq < 2; ++tq)
                acc[tc][tq] = (float4v){0.f, 0.f, 0.f, 0.f};

#pragma unroll
        for (int k4 = 0; k4 < 4; ++k4) {
            short8 a[4];
#pragma unroll
            for (int tc = 0; tc < 4; ++tc) {
                int r = cw * 64 + tc * 16 + l15;       // r&15 == l15
                int seg = k4 * 4 + quad;
                a[tc] = *(const short8*)(&Csh[cbuf][r * 128 + ((seg ^ l15) * 8)]);
            }
#pragma unroll
            for (int tc = 0; tc < 4; ++tc)
#pragma unroll
                for (int tq = 0; tq < 2; ++tq)
                    acc[tc][tq] = __builtin_amdgcn_mfma_f32_16x16x32_bf16(
                        a[tc], bfr[tq][k4], acc[tc][tq], 0, 0, 0);
        }

        // ---- epilogue pass 1: y = c2 - 2*xc (write back into acc), wave min
        float cmin[2] = {3.4e38f, 3.4e38f};
#pragma unroll
        for (int tc = 0; tc < 4; ++tc) {
            float4v c2r = *(const float4v*)(&c2s[cbuf][cw * 64 + tc * 16 + quad * 4]);
#pragma unroll
            for (int tq = 0; tq < 2; ++tq) {
                float y0 = fmaf(-2.0f, acc[tc][tq][0], c2r[0]);
                float y1 = fmaf(-2.0f, acc[tc][tq][1], c2r[1]);
                float y2 = fmaf(-2.0f, acc[tc][tq][2], c2r[2]);
                float y3 = fmaf(-2.0f, acc[tc][tq][3], c2r[3]);
                acc[tc][tq] = (float4v){y0, y1, y2, y3};
                cmin[tq] = fminf(cmin[tq],
                                 fminf(fminf(y0, y1), fminf(y2, y3)));
            }
        }
        // merge wave min across quads (lanes l15/+16/+32/+48 share query q)
#pragma unroll
        for (int tq = 0; tq < 2; ++tq) {
            float v = cmin[tq];
            v = fminf(v, __shfl_xor(v, 16, 64));
            v = fminf(v, __shfl_xor(v, 32, 64));
            cmin[tq] = v;
        }

        // ---- epilogue pass 2: enqueue under te = min(prefix thr, cmin+THR).
        // Superset-safe: if k* in this wave's set, y(k*) <= cmin + 2eps.
        // False positives cost an LDS/global store; drain re-filters.
        float te[2];
#pragma unroll
        for (int tq = 0; tq < 2; ++tq)
            te[tq] = fminf(thr[tq], cmin[tq] + THR);
#pragma unroll
        for (int tc = 0; tc < 4; ++tc) {
#pragma unroll
            for (int tq = 0; tq < 2; ++tq) {
                float4v yv = acc[tc][tq];
                float m4 = fminf(fminf(yv[0], yv[1]), fminf(yv[2], yv[3]));
                if (m4 <= te[tq]) {
#pragma unroll
                    for (int rg = 0; rg < 4; ++rg) {
                        if (yv[rg] <= te[tq]) {
                            unsigned idx  = atomicAdd(&qcnt, 1u);
                            unsigned code = (unsigned)(it * 128 + cw * 64 + tc * 16 + quad * 4 + rg);
                            unsigned q    = (unsigned)(qw * 32 + tq * 16 + l15);
                            unsigned ent  = (q << 11) | code;
                            if (idx < QCAP) {
                                queue[idx]  = ent;
                                queueY[idx] = f2bf_dn(yv[rg]);
                            } else if ((int)(idx - QCAP) < scap) {
                                spillp[idx - QCAP] =
                                    ((unsigned long long)ent << 32) |
                                    (unsigned long long)f2bf_dn(yv[rg]);
                            } else {
                                rescore_one(n, m0 + (int)q, k0 + (int)code,
                                            x, cb32, x2, c2, pmin);
                            }
                        }
                    }
                }
            }
        }

        // ---- merge wave min into minU (already quad-merged)
#pragma unroll
        for (int tq = 0; tq < 2; ++tq) {
            if (quad == 0) {
                unsigned u  = __float_as_uint(cmin[tq]);
                unsigned mu = (u & 0x80000000u) ? ~u : (u | 0x80000000u);
                atomicMin(&minU[qw * 32 + tq * 16 + l15], mu);
            }
        }
        __syncthreads();               // drains stage vmcnt + orders minU/queue
        if (it < 15) {
#pragma unroll
            for (int tq = 0; tq < 2; ++tq) {
                unsigned mu = minU[qw * 32 + tq * 16 + l15];
                unsigned u  = (mu & 0x80000000u) ? (mu & 0x7FFFFFFFu) : ~mu;
                thr[tq] = __uint_as_float(u) + THR;
            }
        }
    }

    // ---- drain: re-filter queue + spill against FINAL per-query threshold,
    // then fp32-rescore survivors. minU complete; last barrier ordered it.
    unsigned total = qcnt;
    unsigned cap = (unsigned)(QCAP + (scap > 0 ? scap : 0));
    if (total > cap) total = cap;
    for (unsigned i = tid; i < total; i += 512) {
        unsigned ent; unsigned short y16;
        if (i < QCAP) { ent = queue[i]; y16 = queueY[i]; }
        else {
            unsigned long long se = spillp[i - QCAP];
            ent = (unsigned)(se >> 32); y16 = (unsigned short)se;
        }
        unsigned q   = ent >> 11;
        unsigned mu  = minU[q];
        unsigned u   = (mu & 0x80000000u) ? (mu & 0x7FFFFFFFu) : ~mu;
        float thrF   = __uint_as_float(u) + THR;
        float yv     = __uint_as_float((unsigned)y16 << 16);
        if (yv <= thrF)
            rescore_one(n, m0 + (int)q, k0 + (int)(ent & 2047u),
                        x, cb32, x2, c2, pmin);
    }
}

// ---------------------------------------------------------------------------
// Gather (transposed): stage selected code rows in LDS, write d-major
// coalesced, read x at same offsets for the loss.
// grid (16, 16): bx=(b<<1)|n, by = 64-wide t-tile. 256 threads.
// ---------------------------------------------------------------------------
__global__ __launch_bounds__(256)
void gather_kernel(const float* __restrict__ x, const float* __restrict__ cb,
                   const unsigned long long* __restrict__ pmin,
                   float* __restrict__ out) {
    __shared__ float Cr[64][DD + 1];   // 33 KB
    __shared__ int   kid[64];
    const int b = blockIdx.x >> 1, n = blockIdx.x & 1;
    const int t0 = blockIdx.y * 64;
    const int tid = threadIdx.x;

    if (tid < 64) {
        int t = t0 + tid;
        int k = (int)(pmin[(size_t)n * MM + b * TT + t] & 0xFFFFFFFFull);
        kid[tid] = k;
        out[OUT_IDX_OFF + (b * NCBN + n) * TT + t] = (float)k;
    }
    __syncthreads();

    {   // stage code rows: 4 lanes per row, coalesced 512 B per row
        int row = tid >> 2, q4 = tid & 3;
        const float* cp = cb + ((size_t)n * KK + kid[row]) * DD + q4 * 32;
#pragma unroll
        for (int j = 0; j < 8; ++j) {
            float4 v = *(const float4*)(cp + j * 4);
            int d = q4 * 32 + j * 4;
            Cr[row][d + 0] = v.x; Cr[row][d + 1] = v.y;
            Cr[row][d + 2] = v.z; Cr[row][d + 3] = v.w;
        }
    }
    __syncthreads();

    float lsum = 0.f;
    const float* xb = x  + ((size_t)(b * 256 + n * 128)) * TT + t0;
    float*       ob = out + ((size_t)(b * 256 + n * 128)) * TT + t0;
#pragma unroll
    for (int pp = 0; pp < 8; ++pp) {
        int u  = tid + pp * 256;       // 2048 units = 128 d x 16 float4
        int d  = u >> 4, ts = (u & 15) * 4;
        float4 xv = *(const float4*)(xb + (size_t)d * TT + ts);
        float4 qv = { Cr[ts + 0][d], Cr[ts + 1][d], Cr[ts + 2][d], Cr[ts + 3][d] };
        *(float4*)(ob + (size_t)d * TT + ts) = qv;
        float e;
        e = xv.x - qv.x; lsum = fmaf(e, e, lsum);
        e = xv.y - qv.y; lsum = fmaf(e, e, lsum);
        e = xv.z - qv.z; lsum = fmaf(e, e, lsum);
        e = xv.w - qv.w; lsum = fmaf(e, e, lsum);
    }

#pragma unroll
    for (int o = 32; o > 0; o >>= 1) lsum += __shfl_down(lsum, o, 64);
    __shared__ float wsum[4];
    int lane = tid & 63, w = tid >> 6;
    if (lane == 0) wsum[w] = lsum;
    __syncthreads();
    if (tid == 0) {
        float tot = wsum[0] + wsum[1] + wsum[2] + wsum[3];
        atomicAdd(out + OUT_LOSS_OFF, tot * 2.384185791015625e-7f);  // 2^-22
    }
}

// ---------------------------------------------------------------------------
extern "C" void kernel_launch(void* const* d_in, const int* in_sizes, int n_in,
                              void* d_out, int out_size, void* d_ws, size_t ws_size,
                              hipStream_t stream) {
    (void)in_sizes; (void)n_in; (void)out_size;
    const float* x  = (const float*)d_in[0];
    const float* cb = (const float*)d_in[1];
    float* out = (float*)d_out;

    char* ws = (char*)d_ws;
    unsigned short* xbf = (unsigned short*)(ws);                       // 4 MiB
    unsigned short* cbf = (unsigned short*)(ws + (4u << 20));          // 4 MiB
    float* x2 = (float*)(ws + (8u << 20));                             // 64 KiB
    float* c2 = (float*)(ws + (8u << 20) + (64u << 10));               // 64 KiB
    unsigned long long* pmin =
        (unsigned long long*)(ws + (8u << 20) + (128u << 10));         // 128 KiB
    size_t spill_off = (8u << 20) + (256u << 10);
    unsigned long long* spill = (unsigned long long*)(ws + spill_off);

    // per-block spill capacity from remaining workspace (0 => inline fallback)
    int scap = 0;
    if (ws_size > spill_off) {
        size_t per_block = (ws_size - spill_off) / (512ull * 8ull);
        scap = (int)(per_block > SCAP ? SCAP : per_block);
    }

    pack_kernel<<<dim3(320), 256, 0, stream>>>(x, cb, xbf, cbf, x2, c2, pmin, out);
    screen_kernel<<<dim3(512), 512, 0, stream>>>(xbf, cbf, c2, x, cb, x2, pmin,
                                                 spill, scap);
    gather_kernel<<<dim3(16, 16), 256, 0, stream>>>(x, cb, pmin, out);
}

// Round 5
// 182.205 us; speedup vs baseline: 1.4048x; 1.4048x over previous
//
#include <hip/hip_runtime.h>
#include <hip/hip_bf16.h>

#define BB   8
#define TT   1024
#define NCBN 2
#define DD   128
#define KK   8192
#define MM   8192          // B*T queries per codebook

constexpr int OUT_IDX_OFF  = BB * 256 * TT;                // 2097152
constexpr int OUT_LOSS_OFF = OUT_IDX_OFF + BB * NCBN * TT; // 2113536

#define THR   0.45f        // >= 2*worst-case |y_bf16 - y_f32| (bound ~0.34)
#define QCAP  2048
#define SCAP  2048         // per-block spill entries in out[] quantized region
// 512 blocks * SCAP * 8B = 8388608 B == OUT_IDX_OFF*4 exactly (fits, no overlap)

typedef __attribute__((ext_vector_type(8))) short   short8;   // 8 bf16
typedef __attribute__((ext_vector_type(4))) float   float4v;

__device__ __forceinline__ unsigned short f2bf(float v) {
    unsigned u = __float_as_uint(v);
    return (unsigned short)((u + 0x7FFFu + ((u >> 16) & 1u)) >> 16);  // RNE
}

// round toward -inf: stored value <= true value (superset-safe screen filter)
__device__ __forceinline__ unsigned short f2bf_dn(float v) {
    unsigned u = __float_as_uint(v);
    unsigned short h = (unsigned short)(u >> 16);
    if ((u & 0x80000000u) && (u & 0xFFFFu)) ++h;   // negative: truncation went up
    return h;
}

__device__ __forceinline__ void gl_lds16(const void* g, void* l) {
    __builtin_amdgcn_global_load_lds(
        (const __attribute__((address_space(1))) unsigned int*)g,
        (__attribute__((address_space(3))) unsigned int*)l, 16, 0, 0);
}

// ---------------------------------------------------------------------------
// Merged pack kernel (one dispatch instead of two):
//   blocks 0..255  : pack_x role — transpose (B,256,T) -> xbf bf16 + x2 + pmin
//   blocks 256..319: pack_c role — codebooks -> cbf bf16 + c2 + zero loss slot
// ---------------------------------------------------------------------------
__global__ __launch_bounds__(256)
void pack_kernel(const float* __restrict__ x, const float* __restrict__ cb,
                 unsigned short* __restrict__ xbf, unsigned short* __restrict__ cbf,
                 float* __restrict__ x2, float* __restrict__ c2,
                 unsigned long long* __restrict__ pmin, float* __restrict__ out) {
    __shared__ float Ld[DD][65];
    const int gb  = blockIdx.x;
    const int tid = threadIdx.x;

    if (gb < 256) {
        // ---- pack_x role: bxn = gb&15 -> (b,n); ty = gb>>4 -> t-tile
        const int bxn = gb & 15, ty = gb >> 4;
        const int b = bxn >> 1, n = bxn & 1;
        const int t0 = ty * 64;

        const float* base = x + ((size_t)(b * 256 + n * 128)) * TT + t0;
        const int dro = tid >> 2, q4 = tid & 3;
#pragma unroll
        for (int half = 0; half < 2; ++half) {
            int d = dro + half * 64;
            const float* rp = base + (size_t)d * TT + q4 * 16;
#pragma unroll
            for (int j = 0; j < 4; ++j) {
                float4 v = *(const float4*)(rp + j * 4);
                int t = q4 * 16 + j * 4;
                Ld[d][t + 0] = v.x; Ld[d][t + 1] = v.y;
                Ld[d][t + 2] = v.z; Ld[d][t + 3] = v.w;
            }
        }
        __syncthreads();

        if (tid < 64) {
            float s = 0.f;
            for (int d = 0; d < DD; ++d) { float v = Ld[d][tid]; s = fmaf(v, v, s); }
            x2[(size_t)n * MM + b * TT + t0 + tid] = s;
            pmin[(size_t)n * MM + b * TT + t0 + tid] = 0xFFFFFFFFFFFFFFFFull;
        }

        unsigned short* orow0 = xbf + ((size_t)n * MM + b * TT + t0) * DD;
#pragma unroll
        for (int pp = 0; pp < 4; ++pp) {
            int u = tid + pp * 256;            // 1024 units = 64 rows x 16 segs
            int tt = u >> 4, sg = u & 15;
            unsigned short tmp[8];
#pragma unroll
            for (int j = 0; j < 8; ++j) tmp[j] = f2bf(Ld[sg * 8 + j][tt]);
            uint4 pk;
            pk.x = (unsigned)tmp[0] | ((unsigned)tmp[1] << 16);
            pk.y = (unsigned)tmp[2] | ((unsigned)tmp[3] << 16);
            pk.z = (unsigned)tmp[4] | ((unsigned)tmp[5] << 16);
            pk.w = (unsigned)tmp[6] | ((unsigned)tmp[7] << 16);
            *(uint4*)(orow0 + (size_t)tt * DD + sg * 8) = pk;
        }
    } else {
        // ---- pack_c role
        int g = (gb - 256) * 256 + tid;        // n*K + k
        if (g == 0) out[OUT_LOSS_OFF] = 0.f;
        const float4* crow = (const float4*)(cb + (size_t)g * DD);
        unsigned short* orow = cbf + (size_t)g * DD;
        float s = 0.f;
#pragma unroll 4
        for (int i2 = 0; i2 < 16; ++i2) {
            float4 v0 = crow[2 * i2];
            float4 v1 = crow[2 * i2 + 1];
            s = fmaf(v0.x, v0.x, s); s = fmaf(v0.y, v0.y, s);
            s = fmaf(v0.z, v0.z, s); s = fmaf(v0.w, v0.w, s);
            s = fmaf(v1.x, v1.x, s); s = fmaf(v1.y, v1.y, s);
            s = fmaf(v1.z, v1.z, s); s = fmaf(v1.w, v1.w, s);
            uint4 pk;
            pk.x = (unsigned)f2bf(v0.x) | ((unsigned)f2bf(v0.y) << 16);
            pk.y = (unsigned)f2bf(v0.z) | ((unsigned)f2bf(v0.w) << 16);
            pk.z = (unsigned)f2bf(v1.x) | ((unsigned)f2bf(v1.y) << 16);
            pk.w = (unsigned)f2bf(v1.z) | ((unsigned)f2bf(v1.w) << 16);
            *(uint4*)(orow + i2 * 8) = pk;
        }
        c2[g] = s;
    }
}

// ---------------------------------------------------------------------------
// Exact fp32 rescore: identical association to the R1 passing kernel.
// atomicMin on packed (s_bits<<32 | k) = "min s, then lowest k" (s > 0 here).
// ---------------------------------------------------------------------------
__device__ void rescore_one(int n, int m, int k,
                            const float* __restrict__ x, const float* __restrict__ cb,
                            const float* __restrict__ x2, const float* __restrict__ c2,
                            unsigned long long* __restrict__ pmin) {
    int b = m >> 10, t = m & (TT - 1);
    const float* xp = x + ((size_t)(b * 256 + n * 128)) * TT + t;
    const float* cp = cb + ((size_t)(n * KK + k)) * DD;
    float xc = 0.f;
    for (int d = 0; d < DD; ++d)
        xc = fmaf(xp[(size_t)d * TT], cp[d], xc);
    float u = x2[n * MM + m] - 2.0f * xc;
    float s = u + c2[n * KK + k];
    unsigned long long pk = ((unsigned long long)__float_as_uint(s) << 32) | (unsigned)k;
    atomicMin(pmin + (size_t)n * MM + m, pk);
}

// ---------------------------------------------------------------------------
// Screening v10 = v8's proven 17-iteration schedule (it=0 min-only on chunk 0,
// chunks 1..15 under prefix thr, chunk 0 revisited last under tightest thr)
// with two safe deltas:
//   (a) overflow past QCAP goes to a GUARANTEED spill region: the out[]
//       quantized area (dead until gather_kernel overwrites all of it).
//       No in-loop serial rescore unless > QCAP+SCAP (=4096) candidates.
//   (b) wave tightener te = min(prefix thr, cmin_wave + THR). Superset-safe:
//       if k* is in this wave's 64-code set, y(k*) <= cmin + 2eps <= te.
// Drain re-filters queue+spill against the FINAL per-query threshold before
// any fp32 rescore (stored y rounded toward -inf, so filter is superset-safe).
// grid 512 x 512 threads (2 blocks/CU). combo = id&7 -> (n,ks) per XCD.
// ---------------------------------------------------------------------------
__global__ __launch_bounds__(512, 4)
void screen_kernel(const unsigned short* __restrict__ xbf,
                   const unsigned short* __restrict__ cbf,
                   const float* __restrict__ c2,
                   const float* __restrict__ x,
                   const float* __restrict__ cb32,
                   const float* __restrict__ x2,
                   unsigned long long* __restrict__ pmin,
                   unsigned long long* __restrict__ spill) {
    __shared__ __align__(16) unsigned short Csh[2][128 * 128];  // 64 KB
    __shared__ float          c2s[2][128];                      // 1 KB
    __shared__ unsigned int   minU[128];
    __shared__ unsigned int   qcnt;
    __shared__ unsigned int   queue[QCAP];                      // 8 KB
    __shared__ unsigned short queueY[QCAP];                     // 4 KB

    const int tid = threadIdx.x;
    const int id  = blockIdx.x;
    const int n   = id & 1;
    const int ks  = (id >> 1) & 3;
    const int qt  = id >> 3;           // 0..63
    const int m0  = qt * 128;
    const int k0  = ks * 2048;

    const int wave = tid >> 6, lane = tid & 63;
    const int cw = wave & 1, qw = wave >> 1;       // cw: 2x64 codes, qw: 4x32 queries
    const int quad = lane >> 4, l15 = lane & 15;

    unsigned long long* spillp = spill + (size_t)id * SCAP;

    // per-lane staging offsets (bytes within one 32 KB tile), 4 issues/wave
    int goff[4];
#pragma unroll
    for (int p = 0; p < 4; ++p) {
        int u   = (p * 8 + wave) * 64 + lane;
        int row = u >> 4;
        int seg = (u & 15) ^ (row & 15);
        goff[p] = (row * DD + seg * 8) * 2;
    }

    const char*  asrc0 = (const char*)(cbf + ((size_t)n * KK + k0) * DD);
    const float* c2p   = c2 + (size_t)n * KK + k0;

    // ---- prologue: stage queries -> Csh[0], code chunk 0 -> Csh[1] (async)
    {
        const char* qsrc = (const char*)(xbf + ((size_t)n * MM + m0) * DD);
#pragma unroll
        for (int p = 0; p < 4; ++p)
            gl_lds16(qsrc + goff[p], &Csh[0][(p * 8 + wave) * 512]);
#pragma unroll
        for (int p = 0; p < 4; ++p)
            gl_lds16(asrc0 + goff[p], &Csh[1][(p * 8 + wave) * 512]);
    }
    if (tid < 32)  *(float4*)&c2s[1][tid * 4] = *(const float4*)(c2p + tid * 4);
    if (tid < 128) minU[tid] = 0xFFFFFFFFu;
    if (tid == 0)  qcnt = 0;
    __syncthreads();                   // both stages + c2s drained

    // ---- query B-fragments (whole D=128) register-resident: 32 VGPRs
    short8 bfr[2][4];                      // [tq][k4]
#pragma unroll
    for (int tq = 0; tq < 2; ++tq) {
        int q = qw * 32 + tq * 16 + l15;   // q&15 == l15
#pragma unroll
        for (int k4 = 0; k4 < 4; ++k4) {
            int seg = k4 * 4 + quad;
            bfr[tq][k4] = *(const short8*)(&Csh[0][q * 128 + ((seg ^ l15) * 8)]);
        }
    }
    __syncthreads();                   // bfr reads done; Csh[0] reusable

    float thr[2] = {3.4e38f, 3.4e38f};

    for (int it = 0; it <= 16; ++it) {
        const int sb   = it & 1;       // stage buffer (next chunk)
        const int cbuf = sb ^ 1;       // compute buffer (current chunk)
        const int dcur = (it < 16) ? it : 0;          // it=0: min-only pass

        if (it < 16) {                 // issue next-chunk stage (wraps to 0)
            const int dn = (it + 1 < 16) ? (it + 1) : 0;
            const char* src = asrc0 + (size_t)dn * (128 * DD * 2);
#pragma unroll
            for (int p = 0; p < 4; ++p)
                gl_lds16(src + goff[p], &Csh[sb][(p * 8 + wave) * 512]);
            if (tid < 32)
                *(float4*)&c2s[sb][tid * 4] =
                    *(const float4*)(c2p + dn * 128 + tid * 4);
        }

        // ---- compute chunk dcur from Csh[cbuf]: 32 MFMA/wave
        float4v acc[4][2];             // [tc][tq]: 32 VGPRs
#pragma unroll
        for (int tc = 0; tc < 4; ++tc)
#pragma unroll
            for (int tq = 0; tq < 2; ++tq)
                acc[tc][tq] = (float4v){0.f, 0.f, 0.f, 0.f};

#pragma unroll
        for (int k4 = 0; k4 < 4; ++k4) {
            short8 a[4];
#pragma unroll
            for (int tc = 0; tc < 4; ++tc) {
                int r = cw * 64 + tc * 16 + l15;       // r&15 == l15
                int seg = k4 * 4 + quad;
                a[tc] = *(const short8*)(&Csh[cbuf][r * 128 + ((seg ^ l15) * 8)]);
            }
#pragma unroll
            for (int tc = 0; tc < 4; ++tc)
#pragma unroll
                for (int tq = 0; tq < 2; ++tq)
                    acc[tc][tq] = __builtin_amdgcn_mfma_f32_16x16x32_bf16(
                        a[tc], bfr[tq][k4], acc[tc][tq], 0, 0, 0);
        }

        // ---- epilogue pass 1: y = c2 - 2*xc (write back into acc), wave min
        float cmin[2] = {3.4e38f, 3.4e38f};
#pragma unroll
        for (int tc = 0; tc < 4; ++tc) {
            float4v c2r = *(const float4v*)(&c2s[cbuf][cw * 64 + tc * 16 + quad * 4]);
#pragma unroll
            for (int tq = 0; tq < 2; ++tq) {
                float y0 = fmaf(-2.0f, acc[tc][tq][0], c2r[0]);
                float y1 = fmaf(-2.0f, acc[tc][tq][1], c2r[1]);
                float y2 = fmaf(-2.0f, acc[tc][tq][2], c2r[2]);
                float y3 = fmaf(-2.0f, acc[tc][tq][3], c2r[3]);
                acc[tc][tq] = (float4v){y0, y1, y2, y3};
                cmin[tq] = fminf(cmin[tq],
                                 fminf(fminf(y0, y1), fminf(y2, y3)));
            }
        }
        // merge wave min across quads (lanes l15/+16/+32/+48 share query q)
#pragma unroll
        for (int tq = 0; tq < 2; ++tq) {
            float v = cmin[tq];
            v = fminf(v, __shfl_xor(v, 16, 64));
            v = fminf(v, __shfl_xor(v, 32, 64));
            cmin[tq] = v;
        }

        // ---- epilogue pass 2 (it>0): enqueue under te = min(thr, cmin+THR).
        // False positives cost an LDS/global store; drain re-filters to final.
        if (it > 0) {
            float te[2];
#pragma unroll
            for (int tq = 0; tq < 2; ++tq)
                te[tq] = fminf(thr[tq], cmin[tq] + THR);
#pragma unroll
            for (int tc = 0; tc < 4; ++tc) {
#pragma unroll
                for (int tq = 0; tq < 2; ++tq) {
                    float4v yv = acc[tc][tq];
                    float m4 = fminf(fminf(yv[0], yv[1]), fminf(yv[2], yv[3]));
                    if (m4 <= te[tq]) {
#pragma unroll
                        for (int rg = 0; rg < 4; ++rg) {
                            if (yv[rg] <= te[tq]) {
                                unsigned idx  = atomicAdd(&qcnt, 1u);
                                unsigned code = (unsigned)(dcur * 128 + cw * 64 + tc * 16 + quad * 4 + rg);
                                unsigned q    = (unsigned)(qw * 32 + tq * 16 + l15);
                                unsigned ent  = (q << 11) | code;
                                if (idx < QCAP) {
                                    queue[idx]  = ent;
                                    queueY[idx] = f2bf_dn(yv[rg]);
                                } else if (idx < QCAP + SCAP) {
                                    spillp[idx - QCAP] =
                                        ((unsigned long long)ent << 32) |
                                        (unsigned long long)f2bf_dn(yv[rg]);
                                } else {
                                    rescore_one(n, m0 + (int)q, k0 + (int)code,
                                                x, cb32, x2, c2, pmin);
                                }
                            }
                        }
                    }
                }
            }
        }

        // ---- merge wave min into minU (already quad-merged)
        if (it < 16) {
#pragma unroll
            for (int tq = 0; tq < 2; ++tq) {
                if (quad == 0) {
                    unsigned u  = __float_as_uint(cmin[tq]);
                    unsigned mu = (u & 0x80000000u) ? ~u : (u | 0x80000000u);
                    atomicMin(&minU[qw * 32 + tq * 16 + l15], mu);
                }
            }
        }
        __syncthreads();               // drains stage vmcnt + orders minU/queue
        if (it < 16) {
#pragma unroll
            for (int tq = 0; tq < 2; ++tq) {
                unsigned mu = minU[qw * 32 + tq * 16 + l15];
                unsigned u  = (mu & 0x80000000u) ? (mu & 0x7FFFFFFFu) : ~mu;
                thr[tq] = __uint_as_float(u) + THR;
            }
        }
    }

    // ---- drain: re-filter queue + spill against FINAL per-query threshold,
    // then fp32-rescore survivors. minU complete; last barrier ordered it.
    unsigned total = qcnt;
    if (total > (unsigned)(QCAP + SCAP)) total = QCAP + SCAP;
    for (unsigned i = tid; i < total; i += 512) {
        unsigned ent; unsigned short y16;
        if (i < QCAP) { ent = queue[i]; y16 = queueY[i]; }
        else {
            unsigned long long se = spillp[i - QCAP];
            ent = (unsigned)(se >> 32); y16 = (unsigned short)se;
        }
        unsigned q   = ent >> 11;
        unsigned mu  = minU[q];
        unsigned u   = (mu & 0x80000000u) ? (mu & 0x7FFFFFFFu) : ~mu;
        float thrF   = __uint_as_float(u) + THR;
        float yv     = __uint_as_float((unsigned)y16 << 16);
        if (yv <= thrF)
            rescore_one(n, m0 + (int)q, k0 + (int)(ent & 2047u),
                        x, cb32, x2, c2, pmin);
    }
}

// ---------------------------------------------------------------------------
// Gather (transposed): stage selected code rows in LDS, write d-major
// coalesced, read x at same offsets for the loss. Overwrites the whole
// quantized region (which screen used as spill scratch).
// grid (16, 16): bx=(b<<1)|n, by = 64-wide t-tile. 256 threads.
// ---------------------------------------------------------------------------
__global__ __launch_bounds__(256)
void gather_kernel(const float* __restrict__ x, const float* __restrict__ cb,
                   const unsigned long long* __restrict__ pmin,
                   float* __restrict__ out) {
    __shared__ float Cr[64][DD + 1];   // 33 KB
    __shared__ int   kid[64];
    const int b = blockIdx.x >> 1, n = blockIdx.x & 1;
    const int t0 = blockIdx.y * 64;
    const int tid = threadIdx.x;

    if (tid < 64) {
        int t = t0 + tid;
        int k = (int)(pmin[(size_t)n * MM + b * TT + t] & 0xFFFFFFFFull);
        kid[tid] = k;
        out[OUT_IDX_OFF + (b * NCBN + n) * TT + t] = (float)k;
    }
    __syncthreads();

    {   // stage code rows: 4 lanes per row, coalesced 512 B per row
        int row = tid >> 2, q4 = tid & 3;
        const float* cp = cb + ((size_t)n * KK + kid[row]) * DD + q4 * 32;
#pragma unroll
        for (int j = 0; j < 8; ++j) {
            float4 v = *(const float4*)(cp + j * 4);
            int d = q4 * 32 + j * 4;
            Cr[row][d + 0] = v.x; Cr[row][d + 1] = v.y;
            Cr[row][d + 2] = v.z; Cr[row][d + 3] = v.w;
        }
    }
    __syncthreads();

    float lsum = 0.f;
    const float* xb = x  + ((size_t)(b * 256 + n * 128)) * TT + t0;
    float*       ob = out + ((size_t)(b * 256 + n * 128)) * TT + t0;
#pragma unroll
    for (int pp = 0; pp < 8; ++pp) {
        int u  = tid + pp * 256;       // 2048 units = 128 d x 16 float4
        int d  = u >> 4, ts = (u & 15) * 4;
        float4 xv = *(const float4*)(xb + (size_t)d * TT + ts);
        float4 qv = { Cr[ts + 0][d], Cr[ts + 1][d], Cr[ts + 2][d], Cr[ts + 3][d] };
        *(float4*)(ob + (size_t)d * TT + ts) = qv;
        float e;
        e = xv.x - qv.x; lsum = fmaf(e, e, lsum);
        e = xv.y - qv.y; lsum = fmaf(e, e, lsum);
        e = xv.z - qv.z; lsum = fmaf(e, e, lsum);
        e = xv.w - qv.w; lsum = fmaf(e, e, lsum);
    }

#pragma unroll
    for (int o = 32; o > 0; o >>= 1) lsum += __shfl_down(lsum, o, 64);
    __shared__ float wsum[4];
    int lane = tid & 63, w = tid >> 6;
    if (lane == 0) wsum[w] = lsum;
    __syncthreads();
    if (tid == 0) {
        float tot = wsum[0] + wsum[1] + wsum[2] + wsum[3];
        atomicAdd(out + OUT_LOSS_OFF, tot * 2.384185791015625e-7f);  // 2^-22
    }
}

// ---------------------------------------------------------------------------
extern "C" void kernel_launch(void* const* d_in, const int* in_sizes, int n_in,
                              void* d_out, int out_size, void* d_ws, size_t ws_size,
                              hipStream_t stream) {
    (void)in_sizes; (void)n_in; (void)out_size; (void)ws_size;
    const float* x  = (const float*)d_in[0];
    const float* cb = (const float*)d_in[1];
    float* out = (float*)d_out;

    char* ws = (char*)d_ws;
    unsigned short* xbf = (unsigned short*)(ws);                       // 4 MiB
    unsigned short* cbf = (unsigned short*)(ws + (4u << 20));          // 4 MiB
    float* x2 = (float*)(ws + (8u << 20));                             // 64 KiB
    float* c2 = (float*)(ws + (8u << 20) + (64u << 10));               // 64 KiB
    unsigned long long* pmin =
        (unsigned long long*)(ws + (8u << 20) + (128u << 10));         // 128 KiB

    // Spill lives in out[] quantized region (floats [0, OUT_IDX_OFF)):
    // 512 blocks * 2048 entries * 8 B = 8388608 B = OUT_IDX_OFF*4 exactly.
    // Dead until gather_kernel, which overwrites every element afterward.
    unsigned long long* spill = (unsigned long long*)out;

    pack_kernel<<<dim3(320), 256, 0, stream>>>(x, cb, xbf, cbf, x2, c2, pmin, out);
    screen_kernel<<<dim3(512), 512, 0, stream>>>(xbf, cbf, c2, x, cb, x2, pmin,
                                                 spill);
    gather_kernel<<<dim3(16, 16), 256, 0, stream>>>(x, cb, pmin, out);
}